// Round 7
// baseline (1123.613 us; speedup 1.0000x reference)
//
#include <hip/hip_runtime.h>

#define H 128
#define H2 256
#define NODE_IN 32
#define BN_EPS 1e-5f

typedef __bf16 bf16x8 __attribute__((ext_vector_type(8)));
typedef __bf16 bf16x4 __attribute__((ext_vector_type(4)));
typedef float f32x4 __attribute__((ext_vector_type(4)));
typedef uint32_t u32x4 __attribute__((ext_vector_type(4)));

#define MFMA(a, b, c) __builtin_amdgcn_mfma_f32_16x16x32_bf16(a, b, c, 0, 0, 0)

// LDS map for mlp kernel
#define W2OFF 65536
#define B1OFF 131072
#define B2OFF 132096
#define STOFF 132608
#define LDSSZ 133632

// ---------------------------------------------------------------------------
// Weights -> bf16, transposed, XOR-swizzled GLOBAL layout (consumed linearly
// by global_load_lds so the LDS copy is swizzled; reads use chunk^(row&7)).
// W1 [L][128][256] -> per layer at l*131072       : row n(0..255) x 256B
// W2 [L][256][128] -> per layer at l*131072+65536 : row n(0..127) x 512B
__global__ __launch_bounds__(256) void convert_weights_kernel(
    const float* __restrict__ W1, const float* __restrict__ W2,
    char* __restrict__ Ws, int L)
{
    int idx = blockIdx.x * 256 + threadIdx.x;
    int per = H * H2;
    int total = L * per;
    if (idx < total) {
        int l = idx / per, r = idx % per;
        int k = r / H2, n = r % H2;          // W1[l][k][n]
        int c = k >> 3, e = k & 7;
        size_t off = (size_t)l * 131072 + n * 256 + (((c ^ (n & 7)) << 4)) + e * 2;
        *(__bf16*)(Ws + off) = (__bf16)W1[idx];
    } else if (idx < 2 * total) {
        int j = idx - total;
        int l = j / per, r = j % per;
        int k = r / H, n = r % H;            // W2[l][k][n]
        int c = k >> 3, e = k & 7;
        size_t off = (size_t)l * 131072 + 65536 + n * 512 + (((c ^ (n & 7)) << 4)) + e * 2;
        *(__bf16*)(Ws + off) = (__bf16)W2[j];
    }
}

// ---------------------------------------------------------------------------
// h0 = x @ emb_W + emb_b  (bf16 out)
__global__ __launch_bounds__(256) void embed_kernel(
    const float* __restrict__ x, const float* __restrict__ W,
    const float* __restrict__ bias, __bf16* __restrict__ h, int N)
{
    __shared__ float xs[16][NODE_IN + 4];
    int row0 = blockIdx.x * 16;
    int t = threadIdx.x;
    if (t < 128) {
        int r = t >> 3, c4 = t & 7;
        int gr = row0 + r;
        float4 v = make_float4(0.f, 0.f, 0.f, 0.f);
        if (gr < N) v = *(const float4*)&x[(size_t)gr * NODE_IN + c4 * 4];
        *(float4*)&xs[r][c4 * 4] = v;
    }
    __syncthreads();
    int c = t & (H - 1);
    int rg = t >> 7;
    int r0 = rg * 8;
    float acc[8] = {0, 0, 0, 0, 0, 0, 0, 0};
    for (int k = 0; k < NODE_IN; ++k) {
        float w = W[k * H + c];
#pragma unroll
        for (int r = 0; r < 8; ++r) acc[r] += xs[r0 + r][k] * w;
    }
    float bb = bias[c];
#pragma unroll
    for (int r = 0; r < 8; ++r) {
        int gr = row0 + r0 + r;
        if (gr < N) h[(size_t)gr * H + c] = (__bf16)(acc[r] + bb);
    }
}

// ---------------------------------------------------------------------------
// CSR build
__global__ __launch_bounds__(256) void hist_kernel(
    const int* __restrict__ dst, int* __restrict__ deg, int E)
{
    int e = blockIdx.x * 256 + threadIdx.x;
    if (e < E) atomicAdd(&deg[dst[e]], 1);
}

__global__ __launch_bounds__(256) void scan_partial_kernel(
    const int* __restrict__ deg, int* __restrict__ bsum, int N)
{
    __shared__ int red[256];
    int b = blockIdx.x, t = threadIdx.x;
    int base = b * 2048 + t * 8;
    int s = 0;
#pragma unroll
    for (int i = 0; i < 8; ++i) { int idx = base + i; if (idx < N) s += deg[idx]; }
    red[t] = s;
    __syncthreads();
    for (int d = 128; d > 0; d >>= 1) {
        if (t < d) red[t] += red[t + d];
        __syncthreads();
    }
    if (t == 0) bsum[b] = red[0];
}

__global__ __launch_bounds__(256) void scan_bsum_kernel(
    int* __restrict__ bsum, int* __restrict__ total, int numB)
{
    __shared__ int ts[256];
    int t = threadIdx.x;
    int v = (t < numB) ? bsum[t] : 0;
    ts[t] = v;
    __syncthreads();
    for (int d = 1; d < 256; d <<= 1) {
        int u = (t >= d) ? ts[t - d] : 0;
        __syncthreads();
        ts[t] += u;
        __syncthreads();
    }
    if (t < numB) bsum[t] = ts[t] - v;
    if (t == 255) *total = ts[255];
}

__global__ __launch_bounds__(256) void scan_apply_kernel(
    const int* __restrict__ deg, const int* __restrict__ bsum,
    int* __restrict__ offp, int* __restrict__ cursor, int N)
{
    __shared__ int ts[256];
    int b = blockIdx.x, t = threadIdx.x;
    int base = b * 2048 + t * 8;
    int loc[8];
    int s = 0;
#pragma unroll
    for (int i = 0; i < 8; ++i) {
        int idx = base + i;
        loc[i] = (idx < N) ? deg[idx] : 0;
        s += loc[i];
    }
    ts[t] = s;
    __syncthreads();
    for (int d = 1; d < 256; d <<= 1) {
        int u = (t >= d) ? ts[t - d] : 0;
        __syncthreads();
        ts[t] += u;
        __syncthreads();
    }
    int run = bsum[b] + ts[t] - s;
#pragma unroll
    for (int i = 0; i < 8; ++i) {
        int idx = base + i;
        if (idx < N) { offp[idx] = run; cursor[idx] = run; }
        run += loc[i];
    }
}

__global__ __launch_bounds__(256) void fill_kernel(
    const int* __restrict__ src, const int* __restrict__ dst,
    int* __restrict__ cursor, int* __restrict__ srclist, int E)
{
    int e = blockIdx.x * 256 + threadIdx.x;
    if (e < E) {
        int pos = atomicAdd(&cursor[dst[e]], 1);
        srclist[pos] = src[e];
    }
}

// ---------------------------------------------------------------------------
// zg[v] = bf16( f(hin[v]) + sum_{nbr} f(hin[src]) ); f = BN?relu(v*sc+sh):v
// 16 lanes per node, bf16x8 (16B)/lane; plain row-major output.
template <int BN>
__global__ __launch_bounds__(256) void gather_kernel(
    const __bf16* __restrict__ hin, const float* __restrict__ ss,
    const int* __restrict__ offp, const int* __restrict__ srclist,
    __bf16* __restrict__ zg, int N)
{
    int gid = blockIdx.x * 256 + threadIdx.x;
    int v = gid >> 4;
    if (v >= N) return;
    int c16 = gid & 15;
    float sc[8], sh[8];
    if (BN) {
#pragma unroll
        for (int j = 0; j < 8; ++j) { sc[j] = ss[c16 * 8 + j]; sh[j] = ss[H + c16 * 8 + j]; }
    }
    float acc[8];
    bf16x8 sv = *(const bf16x8*)(hin + (size_t)v * H + c16 * 8);
#pragma unroll
    for (int j = 0; j < 8; ++j) {
        float f = (float)sv[j];
        acc[j] = BN ? fmaxf(f * sc[j] + sh[j], 0.f) : f;
    }
    int i0 = offp[v], i1 = offp[v + 1];
    int i = i0;
    for (; i + 1 < i1; i += 2) {
        int s0 = srclist[i], s1 = srclist[i + 1];
        bf16x8 u0 = *(const bf16x8*)(hin + (size_t)s0 * H + c16 * 8);
        bf16x8 u1 = *(const bf16x8*)(hin + (size_t)s1 * H + c16 * 8);
#pragma unroll
        for (int j = 0; j < 8; ++j) {
            float f0 = (float)u0[j], f1 = (float)u1[j];
            if (BN) {
                f0 = fmaxf(f0 * sc[j] + sh[j], 0.f);
                f1 = fmaxf(f1 * sc[j] + sh[j], 0.f);
            }
            acc[j] += f0 + f1;
        }
    }
    if (i < i1) {
        int s0 = srclist[i];
        bf16x8 u0 = *(const bf16x8*)(hin + (size_t)s0 * H + c16 * 8);
#pragma unroll
        for (int j = 0; j < 8; ++j) {
            float f0 = (float)u0[j];
            if (BN) f0 = fmaxf(f0 * sc[j] + sh[j], 0.f);
            acc[j] += f0;
        }
    }
    bf16x8 o;
#pragma unroll
    for (int j = 0; j < 8; ++j) o[j] = (__bf16)acc[j];
    *(bf16x8*)(zg + (size_t)v * H + c16 * 8) = o;
}

// ---------------------------------------------------------------------------
__device__ __forceinline__ uint32_t pack_relu2(float x, float y) {
    __bf16 a = (__bf16)fmaxf(x, 0.f), b = (__bf16)fmaxf(y, 0.f);
    return (uint32_t)__builtin_bit_cast(uint16_t, a) |
           ((uint32_t)__builtin_bit_cast(uint16_t, b) << 16);
}

// ---------------------------------------------------------------------------
// MLP: zp = relu(zg@W1+b1)@W2+b2 (pre-BN) + BN partial stats.
// 256 blocks x 512 thr (1 block/CU). Weights live in LDS (staged once,
// pre-swizzled). After one barrier, waves run INDEPENDENT 32-row tiles:
// zg->reg, GEMM1 (A=W1 frag from LDS, B=act rows), hid kept in registers,
// kg-subgroup shuffle, GEMM2, store. No per-tile block barriers.
__global__ __launch_bounds__(512, 2) void mlp_mfma_kernel(
    const __bf16* __restrict__ zg, __bf16* __restrict__ zpb,
    const char* __restrict__ Ws, const float* __restrict__ b1l,
    const float* __restrict__ b2l, float* __restrict__ stats,
    int N, int T)
{
    __shared__ __align__(16) char lds[LDSSZ];

    int tid = threadIdx.x;
    int w = tid >> 6;
    int lane = tid & 63;
    int l15 = lane & 15, kg = lane >> 4;

    // ---- stage 128KB of swizzled weights: 16 x (512 thr x 16B) ----
#pragma unroll
    for (int i = 0; i < 16; ++i) {
        const char* g = Ws + i * 8192 + tid * 16;
        char* l = lds + i * 8192 + w * 1024;   // wave-uniform base; HW adds lane*16
        __builtin_amdgcn_global_load_lds(
            (const __attribute__((address_space(1))) void*)g,
            (__attribute__((address_space(3))) void*)l, 16, 0, 0);
    }
    float* b1f = (float*)(lds + B1OFF);
    float* b2f = (float*)(lds + B2OFF);
    float* sst = (float*)(lds + STOFF);
    if (tid < 256) { b1f[tid] = b1l[tid]; sst[tid] = 0.f; }
    if (tid < 128) b2f[tid] = b2l[tid];
    __syncthreads();   // weights + biases resident; no more block barriers until end

    float pS[8][4], pQ[8][4];
#pragma unroll
    for (int a = 0; a < 8; ++a)
#pragma unroll
        for (int q = 0; q < 4; ++q) { pS[a][q] = 0.f; pQ[a][q] = 0.f; }

    const int xsw = (l15 & 7) << 4;   // read-side XOR swizzle (byte units)

    for (int t = blockIdx.x * 8 + w; t < T; t += 2048) {
        int rbase = t * 32;

        // ---- zg B-fragments (global -> reg, guarded) ----
        bf16x8 zb[2][4];
#pragma unroll
        for (int rg = 0; rg < 2; ++rg) {
            int r = rbase + rg * 16 + l15;
            bool ok = (r < N);
            const __bf16* zr = zg + (size_t)r * H + kg * 8;
#pragma unroll
            for (int kk = 0; kk < 4; ++kk) {
                bf16x8 v = {};
                if (ok) v = *(const bf16x8*)(zr + kk * 32);
                zb[rg][kk] = v;
            }
        }

        // ---- GEMM1: hid (bf16-packed in regs) ----
        uint32_t pd[2][16][2];
#pragma unroll
        for (int nt = 0; nt < 16; ++nt) {
            f32x4 a0 = {0.f, 0.f, 0.f, 0.f}, a1 = {0.f, 0.f, 0.f, 0.f};
            const char* wrow = lds + (nt * 16 + l15) * 256;
#pragma unroll
            for (int kk = 0; kk < 4; ++kk) {
                bf16x8 aw = *(const bf16x8*)(wrow + (((kk * 4 + kg) << 4) ^ xsw));
                a0 = MFMA(aw, zb[0][kk], a0);
                a1 = MFMA(aw, zb[1][kk], a1);
            }
            float4 bb = *(const float4*)&b1f[nt * 16 + kg * 4];
            pd[0][nt][0] = pack_relu2(a0[0] + bb.x, a0[1] + bb.y);
            pd[0][nt][1] = pack_relu2(a0[2] + bb.z, a0[3] + bb.w);
            pd[1][nt][0] = pack_relu2(a1[0] + bb.x, a1[1] + bb.y);
            pd[1][nt][1] = pack_relu2(a1[2] + bb.z, a1[3] + bb.w);
        }

        // ---- kg-subgroup shuffle: pd -> GEMM2 B-fragments ----
        // col c = kk*32+kg*8+2m: src lane = l15+16*((kg&1)*2+(m>>1)),
        // nt_src = 2kk+(kg>>1), h = m&1
        u32x4 bd[2][8];
#pragma unroll
        for (int kk = 0; kk < 8; ++kk)
#pragma unroll
            for (int m = 0; m < 4; ++m) {
                int sl = l15 + 16 * ((kg & 1) * 2 + (m >> 1));
#pragma unroll
                for (int rg = 0; rg < 2; ++rg) {
                    uint32_t vA = (uint32_t)__shfl((int)pd[rg][2 * kk][m & 1], sl, 64);
                    uint32_t vB = (uint32_t)__shfl((int)pd[rg][2 * kk + 1][m & 1], sl, 64);
                    bd[rg][kk][m] = (kg >= 2) ? vB : vA;
                }
            }

        // ---- GEMM2 + epilogue ----
#pragma unroll
        for (int nt2 = 0; nt2 < 8; ++nt2) {
            f32x4 c0 = {0.f, 0.f, 0.f, 0.f}, c1 = {0.f, 0.f, 0.f, 0.f};
            const char* wrow = lds + W2OFF + (nt2 * 16 + l15) * 512;
#pragma unroll
            for (int kk = 0; kk < 8; ++kk) {
                bf16x8 aw = *(const bf16x8*)(wrow + (((kk * 4 + kg) << 4) ^ xsw));
                c0 = MFMA(aw, __builtin_bit_cast(bf16x8, bd[0][kk]), c0);
                c1 = MFMA(aw, __builtin_bit_cast(bf16x8, bd[1][kk]), c1);
            }
            float4 bb = *(const float4*)&b2f[nt2 * 16 + kg * 4];
#pragma unroll
            for (int rg = 0; rg < 2; ++rg) {
                int r = rbase + rg * 16 + l15;
                if (r < N) {
                    f32x4 cc = rg ? c1 : c0;
                    float v0 = cc[0] + bb.x, v1 = cc[1] + bb.y;
                    float v2 = cc[2] + bb.z, v3 = cc[3] + bb.w;
                    pS[nt2][0] += v0; pQ[nt2][0] += v0 * v0;
                    pS[nt2][1] += v1; pQ[nt2][1] += v1 * v1;
                    pS[nt2][2] += v2; pQ[nt2][2] += v2 * v2;
                    pS[nt2][3] += v3; pQ[nt2][3] += v3 * v3;
                    bf16x4 ov;
                    ov[0] = (__bf16)v0; ov[1] = (__bf16)v1;
                    ov[2] = (__bf16)v2; ov[3] = (__bf16)v3;
                    *(bf16x4*)(zpb + (size_t)r * H + nt2 * 16 + kg * 4) = ov;
                }
            }
        }
    }

    // ---- stats: shfl-reduce over l15 lanes, LDS atomics, then global ----
#pragma unroll
    for (int nt2 = 0; nt2 < 8; ++nt2)
#pragma unroll
        for (int q = 0; q < 4; ++q) {
            float s = pS[nt2][q], u = pQ[nt2][q];
            s += __shfl_xor(s, 1, 64); u += __shfl_xor(u, 1, 64);
            s += __shfl_xor(s, 2, 64); u += __shfl_xor(u, 2, 64);
            s += __shfl_xor(s, 4, 64); u += __shfl_xor(u, 4, 64);
            s += __shfl_xor(s, 8, 64); u += __shfl_xor(u, 8, 64);
            if (l15 == 0) {
                int c = nt2 * 16 + kg * 4 + q;
                atomicAdd(&sst[c], s);
                atomicAdd(&sst[H + c], u);
            }
        }
    __syncthreads();
    if (tid < 256) atomicAdd(&stats[tid], sst[tid]);
}

// ---------------------------------------------------------------------------
__global__ void bn_finalize_kernel(const float* __restrict__ stats,
                                   const float* __restrict__ gamma,
                                   const float* __restrict__ beta,
                                   float* __restrict__ ss, int N)
{
    int j = threadIdx.x;
    float invN = 1.0f / (float)N;
    float mean = stats[j] * invN;
    float var = stats[H + j] * invN - mean * mean;
    float sc = gamma[j] * rsqrtf(var + BN_EPS);
    ss[j] = sc;
    ss[H + j] = beta[j] - mean * sc;
}

// ---------------------------------------------------------------------------
// out = relu(zpb*scale + shift), bf16 -> fp32
__global__ __launch_bounds__(256) void bn_apply_kernel(
    const __bf16* __restrict__ zpb, const float* __restrict__ ss,
    float* __restrict__ out, int N)
{
    size_t i = (size_t)blockIdx.x * 256 + threadIdx.x;   // 8-elem units
    size_t total = (size_t)N * (H / 8);
    if (i >= total) return;
    int c8 = (int)(i & (H / 8 - 1));
    bf16x8 v = *(const bf16x8*)(zpb + i * 8);
    float4 o0, o1;
    const float* scp = &ss[c8 * 8];
    const float* shp = &ss[H + c8 * 8];
    o0.x = fmaxf((float)v[0] * scp[0] + shp[0], 0.f);
    o0.y = fmaxf((float)v[1] * scp[1] + shp[1], 0.f);
    o0.z = fmaxf((float)v[2] * scp[2] + shp[2], 0.f);
    o0.w = fmaxf((float)v[3] * scp[3] + shp[3], 0.f);
    o1.x = fmaxf((float)v[4] * scp[4] + shp[4], 0.f);
    o1.y = fmaxf((float)v[5] * scp[5] + shp[5], 0.f);
    o1.z = fmaxf((float)v[6] * scp[6] + shp[6], 0.f);
    o1.w = fmaxf((float)v[7] * scp[7] + shp[7], 0.f);
    ((float4*)out)[i * 2] = o0;
    ((float4*)out)[i * 2 + 1] = o1;
}

// ---------------------------------------------------------------------------
static inline char* align_up(char* p, size_t a) {
    return (char*)(((uintptr_t)p + a - 1) & ~(uintptr_t)(a - 1));
}

extern "C" void kernel_launch(void* const* d_in, const int* in_sizes, int n_in,
                              void* d_out, int out_size, void* d_ws, size_t ws_size,
                              hipStream_t stream)
{
    const float* x    = (const float*)d_in[0];
    const int*   ei   = (const int*)d_in[1];
    const float* embW = (const float*)d_in[2];
    const float* embb = (const float*)d_in[3];
    const float* W1   = (const float*)d_in[4];
    const float* b1   = (const float*)d_in[5];
    const float* W2   = (const float*)d_in[6];
    const float* b2   = (const float*)d_in[7];
    const float* gamma= (const float*)d_in[8];
    const float* beta = (const float*)d_in[9];

    int N = in_sizes[0] / NODE_IN;
    int E = in_sizes[1] / 2;
    int L = in_sizes[4] / (H * H2);
    const int* src = ei;
    const int* dst = ei + E;

    int numB = (N + 2047) / 2048;
    int T = (N + 31) / 32;           // 32-row tiles

    char* w = (char*)d_ws;
    __bf16* zpb = (__bf16*)w;    w += (size_t)N * H * sizeof(__bf16);
    w = align_up(w, 256);
    __bf16* zgb = (__bf16*)w;    w += (size_t)N * H * sizeof(__bf16);
    w = align_up(w, 256);
    __bf16* h0 = (__bf16*)w;     w += (size_t)N * H * sizeof(__bf16);
    w = align_up(w, 256);
    float* statsAll = (float*)w; w += (size_t)L * 2 * H * sizeof(float);
    float* ss = (float*)w;       w += 2 * H * sizeof(float);
    int* deg = (int*)w;          w += (size_t)N * sizeof(int);
    int* offp = (int*)w;         w += (size_t)(N + 1) * sizeof(int);
    int* cursor = (int*)w;       w += (size_t)N * sizeof(int);
    int* bsum = (int*)w;         w += (size_t)numB * sizeof(int);
    int* srcl = (int*)w;         w += (size_t)E * sizeof(int);
    w = align_up(w, 256);
    char* Ws = w;                w += (size_t)L * 131072;

    float* out = (float*)d_out;

    // ---- once-per-launch prep ----
    int wtotal2 = 2 * L * H * H2;
    convert_weights_kernel<<<(wtotal2 + 255) / 256, 256, 0, stream>>>(W1, W2, Ws, L);
    embed_kernel<<<(N + 15) / 16, 256, 0, stream>>>(x, embW, embb, h0, N);

    hipMemsetAsync(deg, 0, (size_t)N * sizeof(int), stream);
    hipMemsetAsync(statsAll, 0, (size_t)L * 2 * H * sizeof(float), stream);

    hist_kernel<<<(E + 255) / 256, 256, 0, stream>>>(dst, deg, E);
    scan_partial_kernel<<<numB, 256, 0, stream>>>(deg, bsum, N);
    scan_bsum_kernel<<<1, 256, 0, stream>>>(bsum, offp + N, numB);
    scan_apply_kernel<<<numB, 256, 0, stream>>>(deg, bsum, offp, cursor, N);
    fill_kernel<<<(E + 255) / 256, 256, 0, stream>>>(src, dst, cursor, srcl, E);

    int ggrid = (N * 16 + 255) / 256;
    int agrid = (int)(((size_t)N * (H / 8) + 255) / 256);

    for (int l = 0; l < L; ++l) {
        float* stats = statsAll + (size_t)l * 2 * H;
        const __bf16* hin = (l == 0) ? h0 : zpb;
        if (l == 0)
            gather_kernel<0><<<ggrid, 256, 0, stream>>>(hin, nullptr, offp, srcl, zgb, N);
        else
            gather_kernel<1><<<ggrid, 256, 0, stream>>>(hin, ss, offp, srcl, zgb, N);
        mlp_mfma_kernel<<<256, 512, 0, stream>>>(
            zgb, zpb, Ws + (size_t)l * 131072, b1 + (size_t)l * H2,
            b2 + (size_t)l * H, stats, N, T);
        bn_finalize_kernel<<<1, H, 0, stream>>>(
            stats, gamma + (size_t)l * H, beta + (size_t)l * H, ss, N);
    }
    bn_apply_kernel<<<agrid, 256, 0, stream>>>(zpb, ss, out, N);
}

// Round 8
// 624.055 us; speedup vs baseline: 1.8005x; 1.8005x over previous
//
#include <hip/hip_runtime.h>

#define H 128
#define H2 256
#define NODE_IN 32
#define BN_EPS 1e-5f

typedef __bf16 bf16x8 __attribute__((ext_vector_type(8)));
typedef __bf16 bf16x4 __attribute__((ext_vector_type(4)));
typedef float f32x4 __attribute__((ext_vector_type(4)));

#define MFMA(a, b, c) __builtin_amdgcn_mfma_f32_16x16x32_bf16(a, b, c, 0, 0, 0)

// ---------------------------------------------------------------------------
// Weights -> bf16, transposed, XOR-swizzled GLOBAL layout (consumed linearly
// by global_load_lds so the LDS copy is swizzled; reads use chunk^(row&7)).
// W1 [L][128][256] -> per layer at l*131072       : row n(0..255) x 256B
// W2 [L][256][128] -> per layer at l*131072+65536 : row n(0..127) x 512B
__global__ __launch_bounds__(256) void convert_weights_kernel(
    const float* __restrict__ W1, const float* __restrict__ W2,
    char* __restrict__ Ws, int L)
{
    int idx = blockIdx.x * 256 + threadIdx.x;
    int per = H * H2;
    int total = L * per;
    if (idx < total) {
        int l = idx / per, r = idx % per;
        int k = r / H2, n = r % H2;          // W1[l][k][n]
        int c = k >> 3, e = k & 7;
        size_t off = (size_t)l * 131072 + n * 256 + (((c ^ (n & 7)) << 4)) + e * 2;
        *(__bf16*)(Ws + off) = (__bf16)W1[idx];
    } else if (idx < 2 * total) {
        int j = idx - total;
        int l = j / per, r = j % per;
        int k = r / H, n = r % H;            // W2[l][k][n]
        int c = k >> 3, e = k & 7;
        size_t off = (size_t)l * 131072 + 65536 + n * 512 + (((c ^ (n & 7)) << 4)) + e * 2;
        *(__bf16*)(Ws + off) = (__bf16)W2[j];
    }
}

// ---------------------------------------------------------------------------
// h0 = x @ emb_W + emb_b  (bf16 out)
__global__ __launch_bounds__(256) void embed_kernel(
    const float* __restrict__ x, const float* __restrict__ W,
    const float* __restrict__ bias, __bf16* __restrict__ h, int N)
{
    __shared__ float xs[16][NODE_IN + 4];
    int row0 = blockIdx.x * 16;
    int t = threadIdx.x;
    if (t < 128) {
        int r = t >> 3, c4 = t & 7;
        int gr = row0 + r;
        float4 v = make_float4(0.f, 0.f, 0.f, 0.f);
        if (gr < N) v = *(const float4*)&x[(size_t)gr * NODE_IN + c4 * 4];
        *(float4*)&xs[r][c4 * 4] = v;
    }
    __syncthreads();
    int c = t & (H - 1);
    int rg = t >> 7;
    int r0 = rg * 8;
    float acc[8] = {0, 0, 0, 0, 0, 0, 0, 0};
    for (int k = 0; k < NODE_IN; ++k) {
        float w = W[k * H + c];
#pragma unroll
        for (int r = 0; r < 8; ++r) acc[r] += xs[r0 + r][k] * w;
    }
    float bb = bias[c];
#pragma unroll
    for (int r = 0; r < 8; ++r) {
        int gr = row0 + r0 + r;
        if (gr < N) h[(size_t)gr * H + c] = (__bf16)(acc[r] + bb);
    }
}

// ---------------------------------------------------------------------------
// CSR build
__global__ __launch_bounds__(256) void hist_kernel(
    const int* __restrict__ dst, int* __restrict__ deg, int E)
{
    int e = blockIdx.x * 256 + threadIdx.x;
    if (e < E) atomicAdd(&deg[dst[e]], 1);
}

__global__ __launch_bounds__(256) void scan_partial_kernel(
    const int* __restrict__ deg, int* __restrict__ bsum, int N)
{
    __shared__ int red[256];
    int b = blockIdx.x, t = threadIdx.x;
    int base = b * 2048 + t * 8;
    int s = 0;
#pragma unroll
    for (int i = 0; i < 8; ++i) { int idx = base + i; if (idx < N) s += deg[idx]; }
    red[t] = s;
    __syncthreads();
    for (int d = 128; d > 0; d >>= 1) {
        if (t < d) red[t] += red[t + d];
        __syncthreads();
    }
    if (t == 0) bsum[b] = red[0];
}

__global__ __launch_bounds__(256) void scan_bsum_kernel(
    int* __restrict__ bsum, int* __restrict__ total, int numB)
{
    __shared__ int ts[256];
    int t = threadIdx.x;
    int v = (t < numB) ? bsum[t] : 0;
    ts[t] = v;
    __syncthreads();
    for (int d = 1; d < 256; d <<= 1) {
        int u = (t >= d) ? ts[t - d] : 0;
        __syncthreads();
        ts[t] += u;
        __syncthreads();
    }
    if (t < numB) bsum[t] = ts[t] - v;
    if (t == 255) *total = ts[255];
}

__global__ __launch_bounds__(256) void scan_apply_kernel(
    const int* __restrict__ deg, const int* __restrict__ bsum,
    int* __restrict__ offp, int* __restrict__ cursor, int N)
{
    __shared__ int ts[256];
    int b = blockIdx.x, t = threadIdx.x;
    int base = b * 2048 + t * 8;
    int loc[8];
    int s = 0;
#pragma unroll
    for (int i = 0; i < 8; ++i) {
        int idx = base + i;
        loc[i] = (idx < N) ? deg[idx] : 0;
        s += loc[i];
    }
    ts[t] = s;
    __syncthreads();
    for (int d = 1; d < 256; d <<= 1) {
        int u = (t >= d) ? ts[t - d] : 0;
        __syncthreads();
        ts[t] += u;
        __syncthreads();
    }
    int run = bsum[b] + ts[t] - s;
#pragma unroll
    for (int i = 0; i < 8; ++i) {
        int idx = base + i;
        if (idx < N) { offp[idx] = run; cursor[idx] = run; }
        run += loc[i];
    }
}

__global__ __launch_bounds__(256) void fill_kernel(
    const int* __restrict__ src, const int* __restrict__ dst,
    int* __restrict__ cursor, int* __restrict__ srclist, int E)
{
    int e = blockIdx.x * 256 + threadIdx.x;
    if (e < E) {
        int pos = atomicAdd(&cursor[dst[e]], 1);
        srclist[pos] = src[e];
    }
}

// ---------------------------------------------------------------------------
// zg[v] = bf16( f(hin[v]) + sum_{nbr} f(hin[src]) ); f = BN?relu(v*sc+sh):v
template <int BN>
__global__ __launch_bounds__(256) void gather_kernel(
    const __bf16* __restrict__ hin, const float* __restrict__ ss,
    const int* __restrict__ offp, const int* __restrict__ srclist,
    __bf16* __restrict__ zg, int N)
{
    int gid = blockIdx.x * 256 + threadIdx.x;
    int v = gid >> 4;
    if (v >= N) return;
    int c16 = gid & 15;
    float sc[8], sh[8];
    if (BN) {
#pragma unroll
        for (int j = 0; j < 8; ++j) { sc[j] = ss[c16 * 8 + j]; sh[j] = ss[H + c16 * 8 + j]; }
    }
    float acc[8];
    bf16x8 sv = *(const bf16x8*)(hin + (size_t)v * H + c16 * 8);
#pragma unroll
    for (int j = 0; j < 8; ++j) {
        float f = (float)sv[j];
        acc[j] = BN ? fmaxf(f * sc[j] + sh[j], 0.f) : f;
    }
    int i0 = offp[v], i1 = offp[v + 1];
    int i = i0;
    for (; i + 1 < i1; i += 2) {
        int s0 = srclist[i], s1 = srclist[i + 1];
        bf16x8 u0 = *(const bf16x8*)(hin + (size_t)s0 * H + c16 * 8);
        bf16x8 u1 = *(const bf16x8*)(hin + (size_t)s1 * H + c16 * 8);
#pragma unroll
        for (int j = 0; j < 8; ++j) {
            float f0 = (float)u0[j], f1 = (float)u1[j];
            if (BN) {
                f0 = fmaxf(f0 * sc[j] + sh[j], 0.f);
                f1 = fmaxf(f1 * sc[j] + sh[j], 0.f);
            }
            acc[j] += f0 + f1;
        }
    }
    if (i < i1) {
        int s0 = srclist[i];
        bf16x8 u0 = *(const bf16x8*)(hin + (size_t)s0 * H + c16 * 8);
#pragma unroll
        for (int j = 0; j < 8; ++j) {
            float f0 = (float)u0[j];
            if (BN) f0 = fmaxf(f0 * sc[j] + sh[j], 0.f);
            acc[j] += f0;
        }
    }
    bf16x8 o;
#pragma unroll
    for (int j = 0; j < 8; ++j) o[j] = (__bf16)acc[j];
    *(bf16x8*)(zg + (size_t)v * H + c16 * 8) = o;
}

// ---------------------------------------------------------------------------
// GEMM1: hid = relu(zg @ W1 + b1). 8 waves/block; W1 (64KB, swizzled) in LDS;
// one barrier; each wave one independent 16-row tile.
// Swapped MFMA: A = W1 frag (LDS), B = zg rows. D lane -> node l15, 4 cols.
__global__ __launch_bounds__(512, 2) void gemm1_kernel(
    const __bf16* __restrict__ zg, __bf16* __restrict__ hid,
    const char* __restrict__ Ws1, const float* __restrict__ b1l, int N)
{
    __shared__ __align__(16) char lds[65536];
    int tid = threadIdx.x;
    int w = tid >> 6, lane = tid & 63;
    int l15 = lane & 15, kg = lane >> 4;

#pragma unroll
    for (int i = 0; i < 8; ++i) {
        const char* g = Ws1 + i * 8192 + tid * 16;
        char* l = lds + i * 8192 + w * 1024;   // wave-uniform base; HW adds lane*16
        __builtin_amdgcn_global_load_lds(
            (const __attribute__((address_space(1))) void*)g,
            (__attribute__((address_space(3))) void*)l, 16, 0, 0);
    }

    int r = (blockIdx.x * 8 + w) * 16 + l15;
    bool ok = (r < N);

    // B fragments: zg rows (lane l15 = node, kg = k-chunk)
    bf16x8 zb[4];
    {
        const __bf16* zr = zg + (size_t)r * H + kg * 8;
#pragma unroll
        for (int kk = 0; kk < 4; ++kk) {
            bf16x8 v = {};
            if (ok) v = *(const bf16x8*)(zr + kk * 32);
            zb[kk] = v;
        }
    }

    __syncthreads();   // weights resident

    const int xsw = (l15 & 7) << 4;
    __bf16* hr = hid + (size_t)r * H2;
#pragma unroll
    for (int nt = 0; nt < 16; ++nt) {
        f32x4 acc = {0.f, 0.f, 0.f, 0.f};
        const char* wrow = lds + (nt * 16 + l15) * 256;
#pragma unroll
        for (int kk = 0; kk < 4; ++kk) {
            bf16x8 aw = *(const bf16x8*)(wrow + (((kk * 4 + kg) << 4) ^ xsw));
            acc = MFMA(aw, zb[kk], acc);
        }
        if (ok) {
            float4 bb = *(const float4*)&b1l[nt * 16 + kg * 4];
            bf16x4 hv;
            hv[0] = (__bf16)fmaxf(acc[0] + bb.x, 0.f);
            hv[1] = (__bf16)fmaxf(acc[1] + bb.y, 0.f);
            hv[2] = (__bf16)fmaxf(acc[2] + bb.z, 0.f);
            hv[3] = (__bf16)fmaxf(acc[3] + bb.w, 0.f);
            *(bf16x4*)(hr + nt * 16 + kg * 4) = hv;
        }
    }
}

// ---------------------------------------------------------------------------
// GEMM2: zp = hid @ W2 + b2 (pre-BN) + per-wave BN partial sums -> spart.
// Same structure; W2 (64KB) in LDS; stats in registers, shfl-reduced.
__global__ __launch_bounds__(512, 2) void gemm2_kernel(
    const __bf16* __restrict__ hid, __bf16* __restrict__ zpb,
    const char* __restrict__ Ws2, const float* __restrict__ b2l,
    float* __restrict__ spart, int N)
{
    __shared__ __align__(16) char lds[65536];
    int tid = threadIdx.x;
    int w = tid >> 6, lane = tid & 63;
    int l15 = lane & 15, kg = lane >> 4;

#pragma unroll
    for (int i = 0; i < 8; ++i) {
        const char* g = Ws2 + i * 8192 + tid * 16;
        char* l = lds + i * 8192 + w * 1024;
        __builtin_amdgcn_global_load_lds(
            (const __attribute__((address_space(1))) void*)g,
            (__attribute__((address_space(3))) void*)l, 16, 0, 0);
    }

    int r = (blockIdx.x * 8 + w) * 16 + l15;
    bool ok = (r < N);

    bf16x8 bd[8];
    {
        const __bf16* hr = hid + (size_t)r * H2 + kg * 8;
#pragma unroll
        for (int kk = 0; kk < 8; ++kk) {
            bf16x8 v = {};
            if (ok) v = *(const bf16x8*)(hr + kk * 32);
            bd[kk] = v;
        }
    }

    __syncthreads();

    const int xsw = (l15 & 7) << 4;
    float pS[8][4], pQ[8][4];
    __bf16* zr = zpb + (size_t)r * H;
#pragma unroll
    for (int nt2 = 0; nt2 < 8; ++nt2) {
        f32x4 acc = {0.f, 0.f, 0.f, 0.f};
        const char* wrow = lds + (nt2 * 16 + l15) * 512;
#pragma unroll
        for (int kk = 0; kk < 8; ++kk) {
            bf16x8 aw = *(const bf16x8*)(wrow + (((kk * 4 + kg) << 4) ^ xsw));
            acc = MFMA(aw, bd[kk], acc);
        }
        float4 bb = *(const float4*)&b2l[nt2 * 16 + kg * 4];
        float v0 = acc[0] + bb.x, v1 = acc[1] + bb.y;
        float v2 = acc[2] + bb.z, v3 = acc[3] + bb.w;
        if (ok) {
            bf16x4 ov;
            ov[0] = (__bf16)v0; ov[1] = (__bf16)v1;
            ov[2] = (__bf16)v2; ov[3] = (__bf16)v3;
            *(bf16x4*)(zr + nt2 * 16 + kg * 4) = ov;
            pS[nt2][0] = v0; pS[nt2][1] = v1; pS[nt2][2] = v2; pS[nt2][3] = v3;
            pQ[nt2][0] = v0 * v0; pQ[nt2][1] = v1 * v1;
            pQ[nt2][2] = v2 * v2; pQ[nt2][3] = v3 * v3;
        } else {
#pragma unroll
            for (int q = 0; q < 4; ++q) { pS[nt2][q] = 0.f; pQ[nt2][q] = 0.f; }
        }
    }

    // reduce over the 16 l15-lanes of each kg group; write per-wave partials
#pragma unroll
    for (int nt2 = 0; nt2 < 8; ++nt2)
#pragma unroll
        for (int q = 0; q < 4; ++q) {
            float s = pS[nt2][q], u = pQ[nt2][q];
            s += __shfl_xor(s, 1, 64); u += __shfl_xor(u, 1, 64);
            s += __shfl_xor(s, 2, 64); u += __shfl_xor(u, 2, 64);
            s += __shfl_xor(s, 4, 64); u += __shfl_xor(u, 4, 64);
            s += __shfl_xor(s, 8, 64); u += __shfl_xor(u, 8, 64);
            pS[nt2][q] = s; pQ[nt2][q] = u;
        }
    if (l15 == 0) {
        size_t row = (size_t)(blockIdx.x * 8 + w) * 256;
#pragma unroll
        for (int nt2 = 0; nt2 < 8; ++nt2) {
            *(float4*)&spart[row + nt2 * 16 + kg * 4] =
                make_float4(pS[nt2][0], pS[nt2][1], pS[nt2][2], pS[nt2][3]);
            *(float4*)&spart[row + 128 + nt2 * 16 + kg * 4] =
                make_float4(pQ[nt2][0], pQ[nt2][1], pQ[nt2][2], pQ[nt2][3]);
        }
    }
}

// ---------------------------------------------------------------------------
__global__ __launch_bounds__(256) void reduce_stats_kernel(
    const float* __restrict__ spart, float* __restrict__ stats, int R)
{
    int t = threadIdx.x;
    int b = blockIdx.x;
    int per = (R + gridDim.x - 1) / gridDim.x;
    int r0 = b * per, r1 = r0 + per;
    if (r1 > R) r1 = R;
    float s = 0.f;
    for (int r = r0; r < r1; ++r) s += spart[(size_t)r * 256 + t];
    atomicAdd(&stats[t], s);
}

// ---------------------------------------------------------------------------
__global__ void bn_finalize_kernel(const float* __restrict__ stats,
                                   const float* __restrict__ gamma,
                                   const float* __restrict__ beta,
                                   float* __restrict__ ss, int N)
{
    int j = threadIdx.x;
    float invN = 1.0f / (float)N;
    float mean = stats[j] * invN;
    float var = stats[H + j] * invN - mean * mean;
    float sc = gamma[j] * rsqrtf(var + BN_EPS);
    ss[j] = sc;
    ss[H + j] = beta[j] - mean * sc;
}

// ---------------------------------------------------------------------------
// out = relu(zpb*scale + shift), bf16 -> fp32
__global__ __launch_bounds__(256) void bn_apply_kernel(
    const __bf16* __restrict__ zpb, const float* __restrict__ ss,
    float* __restrict__ out, int N)
{
    size_t i = (size_t)blockIdx.x * 256 + threadIdx.x;   // 8-elem units
    size_t total = (size_t)N * (H / 8);
    if (i >= total) return;
    int c8 = (int)(i & (H / 8 - 1));
    bf16x8 v = *(const bf16x8*)(zpb + i * 8);
    float4 o0, o1;
    const float* scp = &ss[c8 * 8];
    const float* shp = &ss[H + c8 * 8];
    o0.x = fmaxf((float)v[0] * scp[0] + shp[0], 0.f);
    o0.y = fmaxf((float)v[1] * scp[1] + shp[1], 0.f);
    o0.z = fmaxf((float)v[2] * scp[2] + shp[2], 0.f);
    o0.w = fmaxf((float)v[3] * scp[3] + shp[3], 0.f);
    o1.x = fmaxf((float)v[4] * scp[4] + shp[4], 0.f);
    o1.y = fmaxf((float)v[5] * scp[5] + shp[5], 0.f);
    o1.z = fmaxf((float)v[6] * scp[6] + shp[6], 0.f);
    o1.w = fmaxf((float)v[7] * scp[7] + shp[7], 0.f);
    ((float4*)out)[i * 2] = o0;
    ((float4*)out)[i * 2 + 1] = o1;
}

// ---------------------------------------------------------------------------
static inline char* align_up(char* p, size_t a) {
    return (char*)(((uintptr_t)p + a - 1) & ~(uintptr_t)(a - 1));
}

extern "C" void kernel_launch(void* const* d_in, const int* in_sizes, int n_in,
                              void* d_out, int out_size, void* d_ws, size_t ws_size,
                              hipStream_t stream)
{
    const float* x    = (const float*)d_in[0];
    const int*   ei   = (const int*)d_in[1];
    const float* embW = (const float*)d_in[2];
    const float* embb = (const float*)d_in[3];
    const float* W1   = (const float*)d_in[4];
    const float* b1   = (const float*)d_in[5];
    const float* W2   = (const float*)d_in[6];
    const float* b2   = (const float*)d_in[7];
    const float* gamma= (const float*)d_in[8];
    const float* beta = (const float*)d_in[9];

    int N = in_sizes[0] / NODE_IN;
    int E = in_sizes[1] / 2;
    int L = in_sizes[4] / (H * H2);
    const int* src = ei;
    const int* dst = ei + E;

    int numB = (N + 2047) / 2048;
    int T = (N + 15) / 16;           // 16-row tiles
    int nblk = (T + 7) / 8;          // 8 tiles (waves) per block
    int R = nblk * 8;                // spart rows
    int Npad = R * 16;               // padded rows for hid

    char* w = (char*)d_ws;
    __bf16* zpb = (__bf16*)w;    w += (size_t)N * H * sizeof(__bf16);   // also h0
    w = align_up(w, 256);
    __bf16* zgb = (__bf16*)w;    w += (size_t)N * H * sizeof(__bf16);
    w = align_up(w, 256);
    __bf16* hid = (__bf16*)w;    w += (size_t)Npad * H2 * sizeof(__bf16);
    w = align_up(w, 256);
    float* spart = (float*)w;    w += (size_t)R * 256 * sizeof(float);
    float* statsAll = (float*)w; w += (size_t)L * 2 * H * sizeof(float);
    float* ss = (float*)w;       w += 2 * H * sizeof(float);
    int* deg = (int*)w;          w += (size_t)N * sizeof(int);
    int* offp = (int*)w;         w += (size_t)(N + 1) * sizeof(int);
    int* cursor = (int*)w;       w += (size_t)N * sizeof(int);
    int* bsum = (int*)w;         w += (size_t)numB * sizeof(int);
    int* srcl = (int*)w;         w += (size_t)E * sizeof(int);
    w = align_up(w, 256);
    char* Ws = w;                w += (size_t)L * 131072;

    float* out = (float*)d_out;
    __bf16* h0 = zpb;            // alias: h0 dead after gather of layer 0

    // ---- once-per-launch prep ----
    int wtotal2 = 2 * L * H * H2;
    convert_weights_kernel<<<(wtotal2 + 255) / 256, 256, 0, stream>>>(W1, W2, Ws, L);
    embed_kernel<<<(N + 15) / 16, 256, 0, stream>>>(x, embW, embb, h0, N);

    hipMemsetAsync(deg, 0, (size_t)N * sizeof(int), stream);
    hipMemsetAsync(statsAll, 0, (size_t)L * 2 * H * sizeof(float), stream);

    hist_kernel<<<(E + 255) / 256, 256, 0, stream>>>(dst, deg, E);
    scan_partial_kernel<<<numB, 256, 0, stream>>>(deg, bsum, N);
    scan_bsum_kernel<<<1, 256, 0, stream>>>(bsum, offp + N, numB);
    scan_apply_kernel<<<numB, 256, 0, stream>>>(deg, bsum, offp, cursor, N);
    fill_kernel<<<(E + 255) / 256, 256, 0, stream>>>(src, dst, cursor, srcl, E);

    int ggrid = (N * 16 + 255) / 256;
    int agrid = (int)(((size_t)N * (H / 8) + 255) / 256);

    for (int l = 0; l < L; ++l) {
        float* stats = statsAll + (size_t)l * 2 * H;
        const __bf16* hin = (l == 0) ? h0 : zpb;
        if (l == 0)
            gather_kernel<0><<<ggrid, 256, 0, stream>>>(hin, nullptr, offp, srcl, zgb, N);
        else
            gather_kernel<1><<<ggrid, 256, 0, stream>>>(hin, ss, offp, srcl, zgb, N);
        gemm1_kernel<<<nblk, 512, 0, stream>>>(
            zgb, hid, Ws + (size_t)l * 131072, b1 + (size_t)l * H2, N);
        gemm2_kernel<<<nblk, 512, 0, stream>>>(
            hid, zpb, Ws + (size_t)l * 131072 + 65536, b2 + (size_t)l * H, spart, N);
        reduce_stats_kernel<<<64, 256, 0, stream>>>(spart, stats, R);
        bn_finalize_kernel<<<1, H, 0, stream>>>(
            stats, gamma + (size_t)l * H, beta + (size_t)l * H, ss, N);
    }
    bn_apply_kernel<<<agrid, 256, 0, stream>>>(zpb, ss, out, N);
}